// Round 3
// baseline (703.221 us; speedup 1.0000x reference)
//
#include <hip/hip_runtime.h>
#include <cstdint>
#include <cstddef>

#define NN 500000            // nodes; 500000 = 16 * 31250 exactly
#define NT (NN / 16)         // 31250 tiles of 16 nodes
#define NBLK 768             // 3 blocks/CU resident (matches launch_bounds min)
#define NWAVE (NBLK * 4)     // 3072 waves, each ~10 contiguous tiles
// IN_CH=64, HEADS=4, OUT_CH=32, F=128 out feats, GH=256 gate hidden, SEGS=1024

typedef __attribute__((ext_vector_type(8))) short short8;   // 8 bf16 (4 VGPRs)
typedef __attribute__((ext_vector_type(4))) float floatx4;  // MFMA accumulator

__device__ __forceinline__ unsigned short f2bf(float f) {
  union { float f; unsigned u; } v; v.f = f;
  unsigned r = v.u + 0x7FFFu + ((v.u >> 16) & 1u);  // RNE
  return (unsigned short)(r >> 16);
}
__device__ __forceinline__ unsigned pack2bf(float a, float b) {
  return (unsigned)f2bf(a) | ((unsigned)f2bf(b) << 16);
}

#define MFMA16(a, b, c) __builtin_amdgcn_mfma_f32_16x16x32_bf16((a), (b), (c), 0, 0, 0)

// ---------------------------------------------------------------------------
// Kernel W: fp32 weights -> bf16 in MFMA A-fragment order (unchanged, verified)
// dst[((mtile*ksteps+ks)*64 + lane)*8 + j] = W[mtile*16+(lane&15)][ks*32+(lane>>4)*8+j]
// ---------------------------------------------------------------------------
__global__ void swizzle_weights(const float* __restrict__ gw1, const float* __restrict__ gw2,
                                const float* __restrict__ mw1, const float* __restrict__ mw2,
                                unsigned short* __restrict__ gw1s, unsigned short* __restrict__ gw2s,
                                unsigned short* __restrict__ mw1s, unsigned short* __restrict__ mw2s) {
  int e = blockIdx.x * 256 + threadIdx.x;   // 45056 total
  const float* src; unsigned short* dst; int ksteps, rows, K, local;
  if (e < 16384)      { src = gw1; dst = gw1s; ksteps = 2; rows = 256; K = 64;  local = e; }
  else if (e < 20480) { src = gw2; dst = gw2s; ksteps = 8; rows = 4;   K = 256; local = e - 16384; }
  else if (e < 28672) { src = mw1; dst = mw1s; ksteps = 2; rows = 128; K = 64;  local = e - 20480; }
  else                { src = mw2; dst = mw2s; ksteps = 4; rows = 128; K = 128; local = e - 28672; }
  int j = local & 7, lane = (local >> 3) & 63, tile = local >> 9;
  int ks = tile % ksteps, mtile = tile / ksteps;
  int row = mtile * 16 + (lane & 15);
  int k   = ks * 32 + ((lane >> 4) & 3) * 8 + j;
  float v = (row < rows) ? src[row * K + k] : 0.0f;   // zero-pad (gw2: 4 rows -> 16)
  dst[local] = f2bf(v);
}

// ---------------------------------------------------------------------------
// Fused kernel, barrier-free: each WAVE owns contiguous 16-node tiles.
// Per tile: x -> regs -> bf16 B-frags; gate L1 (16 mt) -> private LDS;
// gate L2 (K=256) -> escore; MLP L1 (8 mt) -> private LDS (same region);
// MLP L2 (8 mt, K=128) -> cf; seg-loop: acc += e_masked * cf across tiles,
// flush (shfl-reduce + atomics) only at segment boundaries.
// b2 bias is separable: added in finalize. No __syncthreads anywhere.
// ---------------------------------------------------------------------------
__global__ __launch_bounds__(256, 3) void fused_kernel(
    const float* __restrict__ x, const int* __restrict__ batch,
    const unsigned short* __restrict__ gw1s, const unsigned short* __restrict__ gw2s,
    const unsigned short* __restrict__ mw1s, const unsigned short* __restrict__ mw2s,
    const float* __restrict__ prelu_a, const float* __restrict__ b1,
    float* __restrict__ denom, float* __restrict__ out) {
  __shared__ unsigned short hall[4][16 * 264];   // 8448 B per wave, 33792 B/block
  int t = threadIdx.x;
  int wave = t >> 6, lane = t & 63;
  int quad = lane >> 4, lcol = lane & 15;
  unsigned short* hs = hall[wave];               // private per-wave slice
  float slope = prelu_a[0];

  int W = blockIdx.x * 4 + wave;
  int t0 = (int)(((long long)W * NT) / NWAVE);
  int t1 = (int)(((long long)(W + 1) * NT) / NWAVE);

  float acc[8][4];
  float e_sum[4] = {0.f, 0.f, 0.f, 0.f};
#pragma unroll
  for (int mt = 0; mt < 8; ++mt)
#pragma unroll
    for (int r = 0; r < 4; ++r) acc[mt][r] = 0.f;
  int cur_seg = batch[t0 * 16];

  for (int tile = t0; tile < t1; ++tile) {
    int base = tile * 16;
    int segv = batch[base + lcol];

    // ---- x: lane (quad,lcol) loads x[base+lcol][ks*32+quad*8 .. +8], ks=0,1 ----
    const float* xp = x + (size_t)(base + lcol) * 64 + quad * 8;
    float4 v00 = *(const float4*)(xp);
    float4 v01 = *(const float4*)(xp + 4);
    float4 v10 = *(const float4*)(xp + 32);
    float4 v11 = *(const float4*)(xp + 36);
    short8 bx0, bx1;
    {
      union { short8 s; unsigned u[4]; } u0, u1;
      u0.u[0] = pack2bf(v00.x, v00.y); u0.u[1] = pack2bf(v00.z, v00.w);
      u0.u[2] = pack2bf(v01.x, v01.y); u0.u[3] = pack2bf(v01.z, v01.w);
      u1.u[0] = pack2bf(v10.x, v10.y); u1.u[1] = pack2bf(v10.z, v10.w);
      u1.u[2] = pack2bf(v11.x, v11.y); u1.u[3] = pack2bf(v11.z, v11.w);
      bx0 = u0.s; bx1 = u1.s;
    }

    // ---- gate layer1: 16 mtiles, h[wcol][node] -> LDS [node][wcol] stride 264 ----
#pragma unroll
    for (int mt = 0; mt < 16; ++mt) {
      short8 a0 = *(const short8*)(gw1s + ((size_t)(mt * 2 + 0) * 64 + lane) * 8);
      short8 a1 = *(const short8*)(gw1s + ((size_t)(mt * 2 + 1) * 64 + lane) * 8);
      floatx4 cc = {0.f, 0.f, 0.f, 0.f};
      cc = MFMA16(a0, bx0, cc);
      cc = MFMA16(a1, bx1, cc);
      float w0 = (cc[0] >= 0.f) ? cc[0] : slope * cc[0];
      float w1 = (cc[1] >= 0.f) ? cc[1] : slope * cc[1];
      float w2 = (cc[2] >= 0.f) ? cc[2] : slope * cc[2];
      float w3 = (cc[3] >= 0.f) ? cc[3] : slope * cc[3];
      uint2 p; p.x = pack2bf(w0, w1); p.y = pack2bf(w2, w3);
      *(uint2*)(hs + lcol * 264 + mt * 16 + quad * 4) = p;
    }

    // ---- gate layer2: K=256; padded gw2 rows are zero -> exp(0)=1 harmless ----
    floatx4 c2 = {0.f, 0.f, 0.f, 0.f};
#pragma unroll
    for (int ks = 0; ks < 8; ++ks) {
      short8 a = *(const short8*)(gw2s + ((size_t)ks * 64 + lane) * 8);
      short8 b = *(const short8*)(hs + lcol * 264 + ks * 32 + quad * 8);
      c2 = MFMA16(a, b, c2);
    }
    float e0 = __expf(c2[0]);
    float e1 = __expf(c2[1]);
    float e2 = __expf(c2[2]);
    float e3 = __expf(c2[3]);
    // broadcast head escores for node = own lcol (values live on quad0 lanes)
    float eb0 = __shfl(e0, lcol);
    float eb1 = __shfl(e1, lcol);
    float eb2 = __shfl(e2, lcol);
    float eb3 = __shfl(e3, lcol);

    // ---- MLP layer1: 8 mtiles -> LDS [node][fcol] stride 136 (reuses hs) ----
#pragma unroll
    for (int mt = 0; mt < 8; ++mt) {
      short8 a0 = *(const short8*)(mw1s + ((size_t)(mt * 2 + 0) * 64 + lane) * 8);
      short8 a1 = *(const short8*)(mw1s + ((size_t)(mt * 2 + 1) * 64 + lane) * 8);
      float4 bias = *(const float4*)(b1 + mt * 16 + quad * 4);
      floatx4 cc = {0.f, 0.f, 0.f, 0.f};
      cc = MFMA16(a0, bx0, cc);
      cc = MFMA16(a1, bx1, cc);
      uint2 p;
      p.x = pack2bf(fmaxf(cc[0] + bias.x, 0.f), fmaxf(cc[1] + bias.y, 0.f));
      p.y = pack2bf(fmaxf(cc[2] + bias.z, 0.f), fmaxf(cc[3] + bias.w, 0.f));
      *(uint2*)(hs + lcol * 136 + mt * 16 + quad * 4) = p;
    }

    // ---- MLP layer2: 8 mtiles, K=128 -> cf[fcol][node] ----
    short8 bh[4];
#pragma unroll
    for (int ks = 0; ks < 4; ++ks)
      bh[ks] = *(const short8*)(hs + lcol * 136 + ks * 32 + quad * 8);
    float cf[8][4];
#pragma unroll
    for (int mt = 0; mt < 8; ++mt) {
      floatx4 cc = {0.f, 0.f, 0.f, 0.f};
#pragma unroll
      for (int ks = 0; ks < 4; ++ks) {
        short8 a = *(const short8*)(mw2s + ((size_t)(mt * 4 + ks) * 64 + lane) * 8);
        cc = MFMA16(a, bh[ks], cc);
      }
      cf[mt][0] = cc[0]; cf[mt][1] = cc[1]; cf[mt][2] = cc[2]; cf[mt][3] = cc[3];
    }

    // ---- segment loop: masked accumulate; flush only on seg change ----
    int p = 0;
    while (true) {
      int s = __shfl(segv, p);
      if (s != cur_seg) {
        // flush acc + e_sum for cur_seg (reduce over node columns = lcol)
#pragma unroll
        for (int mt = 0; mt < 8; ++mt)
#pragma unroll
          for (int r = 0; r < 4; ++r) {
            float v = acc[mt][r];
            v += __shfl_xor(v, 1); v += __shfl_xor(v, 2);
            v += __shfl_xor(v, 4); v += __shfl_xor(v, 8);
            if (lcol == 0)
              atomicAdd(&out[cur_seg * 128 + mt * 16 + quad * 4 + r], v);
            acc[mt][r] = 0.f;
          }
#pragma unroll
        for (int h = 0; h < 4; ++h) {
          float v = e_sum[h];
          v += __shfl_xor(v, 1); v += __shfl_xor(v, 2);
          v += __shfl_xor(v, 4); v += __shfl_xor(v, 8);
          if (lane == 0) atomicAdd(&denom[cur_seg * 4 + h], v);
          e_sum[h] = 0.f;
        }
        cur_seg = s;
      }
      float m = (segv == s) ? 1.f : 0.f;
      float em[4] = {eb0 * m, eb1 * m, eb2 * m, eb3 * m};
      e_sum[0] += em[0]; e_sum[1] += em[1]; e_sum[2] += em[2]; e_sum[3] += em[3];
#pragma unroll
      for (int mt = 0; mt < 8; ++mt) {
        float e = em[mt >> 1];   // head = fcol>>5 = mt>>1
        acc[mt][0] = fmaf(e, cf[mt][0], acc[mt][0]);
        acc[mt][1] = fmaf(e, cf[mt][1], acc[mt][1]);
        acc[mt][2] = fmaf(e, cf[mt][2], acc[mt][2]);
        acc[mt][3] = fmaf(e, cf[mt][3], acc[mt][3]);
      }
      unsigned long long bl = __ballot(segv == s);
      p += (int)(__popcll(bl) >> 2);   // 4 quads replicate each node
      if (p >= 16) break;
    }
  }

  // final flush
#pragma unroll
  for (int mt = 0; mt < 8; ++mt)
#pragma unroll
    for (int r = 0; r < 4; ++r) {
      float v = acc[mt][r];
      v += __shfl_xor(v, 1); v += __shfl_xor(v, 2);
      v += __shfl_xor(v, 4); v += __shfl_xor(v, 8);
      if (lcol == 0)
        atomicAdd(&out[cur_seg * 128 + mt * 16 + quad * 4 + r], v);
    }
#pragma unroll
  for (int h = 0; h < 4; ++h) {
    float v = e_sum[h];
    v += __shfl_xor(v, 1); v += __shfl_xor(v, 2);
    v += __shfl_xor(v, 4); v += __shfl_xor(v, 8);
    if (lane == 0) atomicAdd(&denom[cur_seg * 4 + h], v);
  }
}

// ---------------------------------------------------------------------------
// Finalize: out = numer / denom + b2  (b2 separable from the pooling sum)
// ---------------------------------------------------------------------------
__global__ void finalize_kernel(float* __restrict__ out, const float* __restrict__ denom,
                                const float* __restrict__ b2) {
  int i = blockIdx.x * 256 + threadIdx.x;   // 131072 = 1024 segs * 128 fcols
  int seg = i >> 7, head = (i >> 5) & 3;
  float d = denom[seg * 4 + head];
  out[i] = (d > 0.f) ? (out[i] / d + b2[i & 127]) : 0.f;
}

// ---------------------------------------------------------------------------
extern "C" void kernel_launch(void* const* d_in, const int* in_sizes, int n_in,
                              void* d_out, int out_size, void* d_ws, size_t ws_size,
                              hipStream_t stream) {
  const float* x     = (const float*)d_in[0];
  const int*   batch = (const int*)d_in[1];
  // d_in[2] = num_segments (constant 1024, unused)
  const float* gw1 = (const float*)d_in[3];
  const float* pa  = (const float*)d_in[4];
  const float* gw2 = (const float*)d_in[5];
  const float* mw1 = (const float*)d_in[6];
  const float* mb1 = (const float*)d_in[7];
  const float* mw2 = (const float*)d_in[8];
  const float* mb2 = (const float*)d_in[9];
  float* out = (float*)d_out;

  char* ws = (char*)d_ws;
  float* denom = (float*)ws;                              // 4096 fp32 = 16,384 B
  unsigned short* gw1s = (unsigned short*)(ws + 16384);   // 32,768 B
  unsigned short* gw2s = (unsigned short*)(ws + 49152);   //  8,192 B
  unsigned short* mw1s = (unsigned short*)(ws + 57344);   // 16,384 B
  unsigned short* mw2s = (unsigned short*)(ws + 73728);   // 32,768 B

  hipMemsetAsync(denom, 0, 4096 * sizeof(float), stream);
  hipMemsetAsync(out, 0, (size_t)out_size * sizeof(float), stream);

  swizzle_weights<<<176, 256, 0, stream>>>(gw1, gw2, mw1, mw2, gw1s, gw2s, mw1s, mw2s);

  fused_kernel<<<NBLK, 256, 0, stream>>>(x, batch, gw1s, gw2s, mw1s, mw2s,
                                         pa, mb1, denom, out);

  finalize_kernel<<<512, 256, 0, stream>>>(out, denom, mb2);
}

// Round 4
// 304.993 us; speedup vs baseline: 2.3057x; 2.3057x over previous
//
#include <hip/hip_runtime.h>
#include <cstdint>
#include <cstddef>

#define NN 500000            // nodes = 16 * 31250 exactly
#define NTILES 31250         // 16-node tiles
#define NG 7813              // 64-node granules (4 tiles; last has 2)
#define NBLK 1024            // 128-thread blocks; 4/CU by LDS -> 8 waves/CU
#define NWAVES (NBLK * 2)
// IN_CH=64, HEADS=4, OUT_CH=32, F=128 out feats, GH=256 gate hidden, SEGS=1024

typedef __attribute__((ext_vector_type(8))) short short8;   // 8 bf16 MFMA frag
typedef __attribute__((ext_vector_type(4))) float floatx4;  // MFMA accumulator
typedef __attribute__((ext_vector_type(4))) float fv4;

__device__ __forceinline__ unsigned short f2bf(float f) {
  union { float f; unsigned u; } v; v.f = f;
  unsigned r = v.u + 0x7FFFu + ((v.u >> 16) & 1u);  // RNE
  return (unsigned short)(r >> 16);
}
__device__ __forceinline__ unsigned pack2bf(float a, float b) {
  return (unsigned)f2bf(a) | ((unsigned)f2bf(b) << 16);
}
__device__ __forceinline__ fv4 ntload4(const float* p) {
  return __builtin_nontemporal_load((const fv4*)p);
}

#define MFMA16(a, b, c) __builtin_amdgcn_mfma_f32_16x16x32_bf16((a), (b), (c), 0, 0, 0)

// ---------------------------------------------------------------------------
// Kernel W: fp32 weights -> bf16 MFMA A-fragment order (gw1 / mw1 / mw2 only;
// gw2 is consumed as fp32 via LDS in the fused kernel).
// dst[((mtile*ksteps+ks)*64+lane)*8+j] = W[mtile*16+(lane&15)][ks*32+(lane>>4)*8+j]
// ---------------------------------------------------------------------------
__global__ void swizzle_weights(const float* __restrict__ gw1, const float* __restrict__ mw1,
                                const float* __restrict__ mw2,
                                unsigned short* __restrict__ gw1s,
                                unsigned short* __restrict__ mw1s,
                                unsigned short* __restrict__ mw2s) {
  int e = blockIdx.x * 256 + threadIdx.x;   // 40960 total
  const float* src; unsigned short* dst; int ksteps, K, local;
  if (e < 16384)      { src = gw1; dst = gw1s; ksteps = 2; K = 64;  local = e; }
  else if (e < 24576) { src = mw1; dst = mw1s; ksteps = 2; K = 64;  local = e - 16384; }
  else                { src = mw2; dst = mw2s; ksteps = 4; K = 128; local = e - 24576; }
  int j = local & 7, lane = (local >> 3) & 63, tile = local >> 9;
  int ks = tile % ksteps, mtile = tile / ksteps;
  int row = mtile * 16 + (lane & 15);
  int k   = ks * 32 + ((lane >> 4) & 3) * 8 + j;
  dst[local] = f2bf(src[row * K + k]);
}

#define FLUSH() do {                                                          \
  _Pragma("unroll") for (int mt_ = 0; mt_ < 8; ++mt_) {                       \
    _Pragma("unroll") for (int r_ = 0; r_ < 4; ++r_) {                        \
      float v_ = acc[mt_][r_];                                                \
      v_ += __shfl_xor(v_, 1); v_ += __shfl_xor(v_, 2);                       \
      v_ += __shfl_xor(v_, 4); v_ += __shfl_xor(v_, 8);                       \
      if (lcol == 0)                                                          \
        atomicAdd(&out[cur_seg * 128 + mt_ * 16 + quad * 4 + r_], v_);        \
      acc[mt_][r_] = 0.f; } }                                                 \
  _Pragma("unroll") for (int h_ = 0; h_ < 4; ++h_) {                          \
    float v_ = e_sum[h_];                                                     \
    v_ += __shfl_xor(v_, 1); v_ += __shfl_xor(v_, 2);                         \
    v_ += __shfl_xor(v_, 4); v_ += __shfl_xor(v_, 8);                         \
    if (lane == 0) atomicAdd(&denom[cur_seg * 4 + h_], v_);                   \
    e_sum[h_] = 0.f; }                                                        \
} while (0)

// ---------------------------------------------------------------------------
// Fused kernel, barrier-free after prologue: each WAVE owns contiguous 64-node
// granules. Weights streamed from global (L2-resident; x is nontemporal so it
// can't evict them), amortized over 4 node-tiles per fragment load.
// Gate L2 (4-wide) fused into gate L1 epilogue in VALU via gw2^T in LDS.
// Segment accumulation in registers, uniform run-loop, flush on seg change.
// ---------------------------------------------------------------------------
__global__ __launch_bounds__(128, 2) void fused_kernel(
    const float* __restrict__ x, const int* __restrict__ batch,
    const unsigned short* __restrict__ gw1s, const unsigned short* __restrict__ mw1s,
    const unsigned short* __restrict__ mw2s, const float* __restrict__ gw2,
    const float* __restrict__ prelu_a, const float* __restrict__ b1,
    float* __restrict__ denom, float* __restrict__ out) {
  __shared__ float gw2L[1024];                   // gw2^T [wcol][head], 4 KB
  __shared__ unsigned short hs_all[2][64 * 132]; // per-wave h1 staging, 2x16.9 KB
  const int t = threadIdx.x;
  const int wave = t >> 6, lane = t & 63;
  const int quad = lane >> 4, lcol = lane & 15;
  unsigned short* hs = hs_all[wave];

  for (int i = t; i < 1024; i += 128) gw2L[i] = gw2[(i & 3) * 256 + (i >> 2)];
  __syncthreads();   // only barrier in the kernel

  const float slope = prelu_a[0];
  const int W = blockIdx.x * 2 + wave;
  const int g0 = (int)(((long long)W * NG) / NWAVES);
  const int g1 = (int)(((long long)(W + 1) * NG) / NWAVES);

  float acc[8][4];
  float e_sum[4] = {0.f, 0.f, 0.f, 0.f};
#pragma unroll
  for (int mt = 0; mt < 8; ++mt)
#pragma unroll
    for (int r = 0; r < 4; ++r) acc[mt][r] = 0.f;
  int fs = g0 * 64; if (fs > NN - 1) fs = NN - 1;
  int cur_seg = batch[fs];

  for (int g = g0; g < g1; ++g) {
    const int base = g * 64;
    int sv[4]; float emask[4];
    short8 bx[4][2];
#pragma unroll
    for (int nt = 0; nt < 4; ++nt) {
      int tb = base + nt * 16;
      bool ok = tb < NN;               // NN%16==0 -> tile fully valid or fully not
      int node = ok ? (tb + lcol) : (NN - 1);
      emask[nt] = ok ? 1.f : 0.f;
      sv[nt] = batch[node];
      const float* xp = x + (size_t)node * 64 + quad * 8;
      fv4 v0 = ntload4(xp), v1 = ntload4(xp + 4);
      fv4 v2 = ntload4(xp + 32), v3 = ntload4(xp + 36);
      union { short8 s; unsigned u[4]; } u0, u1;
      u0.u[0] = pack2bf(v0[0], v0[1]); u0.u[1] = pack2bf(v0[2], v0[3]);
      u0.u[2] = pack2bf(v1[0], v1[1]); u0.u[3] = pack2bf(v1[2], v1[3]);
      u1.u[0] = pack2bf(v2[0], v2[1]); u1.u[1] = pack2bf(v2[2], v2[3]);
      u1.u[2] = pack2bf(v3[0], v3[1]); u1.u[3] = pack2bf(v3[2], v3[3]);
      bx[nt][0] = u0.s; bx[nt][1] = u1.s;
    }

    // ---- gate L1 (MFMA) with fused L2 partials (VALU, gw2L broadcast) ----
    float gp[4][4];
#pragma unroll
    for (int nt = 0; nt < 4; ++nt)
#pragma unroll
      for (int h = 0; h < 4; ++h) gp[nt][h] = 0.f;
#pragma unroll 2
    for (int mt = 0; mt < 16; ++mt) {
      short8 a0 = *(const short8*)(gw1s + ((size_t)(mt * 2 + 0) * 64 + lane) * 8);
      short8 a1 = *(const short8*)(gw1s + ((size_t)(mt * 2 + 1) * 64 + lane) * 8);
      fv4 g2r0 = *(const fv4*)&gw2L[(mt * 16 + quad * 4 + 0) * 4];
      fv4 g2r1 = *(const fv4*)&gw2L[(mt * 16 + quad * 4 + 1) * 4];
      fv4 g2r2 = *(const fv4*)&gw2L[(mt * 16 + quad * 4 + 2) * 4];
      fv4 g2r3 = *(const fv4*)&gw2L[(mt * 16 + quad * 4 + 3) * 4];
#pragma unroll
      for (int nt = 0; nt < 4; ++nt) {
        floatx4 cc = {0.f, 0.f, 0.f, 0.f};
        cc = MFMA16(a0, bx[nt][0], cc);
        cc = MFMA16(a1, bx[nt][1], cc);
        float h0 = cc[0] >= 0.f ? cc[0] : slope * cc[0];
        float h1v = cc[1] >= 0.f ? cc[1] : slope * cc[1];
        float h2 = cc[2] >= 0.f ? cc[2] : slope * cc[2];
        float h3 = cc[3] >= 0.f ? cc[3] : slope * cc[3];
        gp[nt][0] += g2r0[0]*h0 + g2r1[0]*h1v + g2r2[0]*h2 + g2r3[0]*h3;
        gp[nt][1] += g2r0[1]*h0 + g2r1[1]*h1v + g2r2[1]*h2 + g2r3[1]*h3;
        gp[nt][2] += g2r0[2]*h0 + g2r1[2]*h1v + g2r2[2]*h2 + g2r3[2]*h3;
        gp[nt][3] += g2r0[3]*h0 + g2r1[3]*h1v + g2r2[3]*h2 + g2r3[3]*h3;
      }
    }
    float e16[4][4];
#pragma unroll
    for (int nt = 0; nt < 4; ++nt)
#pragma unroll
      for (int h = 0; h < 4; ++h) {
        float v = gp[nt][h];
        v += __shfl_xor(v, 16);      // sum partials across quads
        v += __shfl_xor(v, 32);
        e16[nt][h] = __expf(v) * emask[nt];   // |gate| small -> no max needed
      }

    // ---- MLP L1 (MFMA) -> bf16 staging hs[node][fc], stride 132 ----
#pragma unroll 2
    for (int mt = 0; mt < 8; ++mt) {
      short8 a0 = *(const short8*)(mw1s + ((size_t)(mt * 2 + 0) * 64 + lane) * 8);
      short8 a1 = *(const short8*)(mw1s + ((size_t)(mt * 2 + 1) * 64 + lane) * 8);
      fv4 bias = *(const fv4*)(b1 + mt * 16 + quad * 4);
#pragma unroll
      for (int nt = 0; nt < 4; ++nt) {
        floatx4 cc = {0.f, 0.f, 0.f, 0.f};
        cc = MFMA16(a0, bx[nt][0], cc);
        cc = MFMA16(a1, bx[nt][1], cc);
        uint2 p;
        p.x = pack2bf(fmaxf(cc[0] + bias[0], 0.f), fmaxf(cc[1] + bias[1], 0.f));
        p.y = pack2bf(fmaxf(cc[2] + bias[2], 0.f), fmaxf(cc[3] + bias[3], 0.f));
        *(uint2*)(hs + (nt * 16 + lcol) * 132 + mt * 16 + quad * 4) = p;
      }
    }
    // ---- B-fragments for MLP L2 (wave-internal LDS ordering; no barrier) ----
    union BH { short8 s; uint2 u[2]; } bh[4][4];
#pragma unroll
    for (int nt = 0; nt < 4; ++nt)
#pragma unroll
      for (int ks = 0; ks < 4; ++ks) {
        const unsigned short* hp = hs + (nt * 16 + lcol) * 132 + ks * 32 + quad * 8;
        bh[nt][ks].u[0] = *(const uint2*)hp;
        bh[nt][ks].u[1] = *(const uint2*)(hp + 4);
      }

    // ---- uniform run loop over segments within the 64 nodes ----
    int p = 0;
    while (p < 64) {
      int pn = p >> 4, pl = p & 15;
      int sel = (pn == 0) ? sv[0] : (pn == 1) ? sv[1] : (pn == 2) ? sv[2] : sv[3];
      int s = __shfl(sel, pl);           // seg of first unprocessed node (uniform)
      if (s != cur_seg) { FLUSH(); cur_seg = s; }
      int cnt = 0;
      float em[4][4];
#pragma unroll
      for (int nt = 0; nt < 4; ++nt) {
        bool mm = (sv[nt] == s);
        cnt += (int)__popcll(__ballot(mm));
        float m = mm ? 1.f : 0.f;
#pragma unroll
        for (int h = 0; h < 4; ++h) em[nt][h] = e16[nt][h] * m;
      }
#pragma unroll
      for (int h = 0; h < 4; ++h)
        e_sum[h] += em[0][h] + em[1][h] + em[2][h] + em[3][h];
#pragma unroll
      for (int mt = 0; mt < 8; ++mt) {
        short8 a20 = *(const short8*)(mw2s + ((size_t)(mt * 4 + 0) * 64 + lane) * 8);
        short8 a21 = *(const short8*)(mw2s + ((size_t)(mt * 4 + 1) * 64 + lane) * 8);
        short8 a22 = *(const short8*)(mw2s + ((size_t)(mt * 4 + 2) * 64 + lane) * 8);
        short8 a23 = *(const short8*)(mw2s + ((size_t)(mt * 4 + 3) * 64 + lane) * 8);
        const int hh = mt >> 1;          // head of fcols [mt*16, mt*16+16)
#pragma unroll
        for (int nt = 0; nt < 4; ++nt) {
          floatx4 cc = {0.f, 0.f, 0.f, 0.f};
          cc = MFMA16(a20, bh[nt][0].s, cc);
          cc = MFMA16(a21, bh[nt][1].s, cc);
          cc = MFMA16(a22, bh[nt][2].s, cc);
          cc = MFMA16(a23, bh[nt][3].s, cc);
          float e = em[nt][hh];
          acc[mt][0] = fmaf(e, cc[0], acc[mt][0]);
          acc[mt][1] = fmaf(e, cc[1], acc[mt][1]);
          acc[mt][2] = fmaf(e, cc[2], acc[mt][2]);
          acc[mt][3] = fmaf(e, cc[3], acc[mt][3]);
        }
      }
      p += (cnt >> 2);                   // 4 quads replicate each node
    }
  }
  FLUSH();
}

// ---------------------------------------------------------------------------
// Finalize: out = numer/denom + b2 (b2 separable; scores sum to 1 per seg-head)
// ---------------------------------------------------------------------------
__global__ void finalize_kernel(float* __restrict__ out, const float* __restrict__ denom,
                                const float* __restrict__ b2) {
  int i = blockIdx.x * 256 + threadIdx.x;   // 131072 = 1024 segs * 128 fcols
  int seg = i >> 7, head = (i >> 5) & 3;
  float d = denom[seg * 4 + head];
  out[i] = (d > 0.f) ? (out[i] / d + b2[i & 127]) : 0.f;
}

// ---------------------------------------------------------------------------
extern "C" void kernel_launch(void* const* d_in, const int* in_sizes, int n_in,
                              void* d_out, int out_size, void* d_ws, size_t ws_size,
                              hipStream_t stream) {
  const float* x     = (const float*)d_in[0];
  const int*   batch = (const int*)d_in[1];
  // d_in[2] = num_segments (constant 1024, unused)
  const float* gw1 = (const float*)d_in[3];
  const float* pa  = (const float*)d_in[4];
  const float* gw2 = (const float*)d_in[5];
  const float* mw1 = (const float*)d_in[6];
  const float* mb1 = (const float*)d_in[7];
  const float* mw2 = (const float*)d_in[8];
  const float* mb2 = (const float*)d_in[9];
  float* out = (float*)d_out;

  char* ws = (char*)d_ws;
  float* denom = (float*)ws;                              // 4096 fp32 = 16,384 B
  unsigned short* gw1s = (unsigned short*)(ws + 16384);   // 32,768 B
  unsigned short* mw1s = (unsigned short*)(ws + 49152);   // 16,384 B
  unsigned short* mw2s = (unsigned short*)(ws + 65536);   // 32,768 B

  hipMemsetAsync(denom, 0, 4096 * sizeof(float), stream);
  hipMemsetAsync(out, 0, (size_t)out_size * sizeof(float), stream);

  swizzle_weights<<<160, 256, 0, stream>>>(gw1, mw1, mw2, gw1s, mw1s, mw2s);

  fused_kernel<<<NBLK, 128, 0, stream>>>(x, batch, gw1s, mw1s, mw2s, gw2,
                                         pa, mb1, denom, out);

  finalize_kernel<<<512, 256, 0, stream>>>(out, denom, mb2);
}